// Round 7
// baseline (1210.113 us; speedup 1.0000x reference)
//
#include <hip/hip_runtime.h>
#include <hip/hip_bf16.h>
#include <stdint.h>

// Problem constants
#define TLEN 4096
#define DMm  2048
#define DD   4096
#define DGg  512
#define BT   8192          // B*T
#define DW   16384         // D*W

typedef __attribute__((ext_vector_type(8))) short bf16x8;
typedef __attribute__((ext_vector_type(4))) float f32x4;

__device__ __forceinline__ unsigned short f2bf(float f) {
    union { float f; unsigned u; } c; c.f = f;
    unsigned u = c.u;
    unsigned r = (u + 0x7FFFu + ((u >> 16) & 1u)) >> 16;   // RNE
    return (unsigned short)r;
}

// ---------------- fused cast f32 -> bf16 for gen|w1|w2 (contiguous in ws) ----
#define NB1 (BT * DMm / 4)
#define NB2 (DGg * DMm / 4)
#define NB3 (DW * DGg / 4)
__global__ void cast_all_kernel(const float* __restrict__ g,
                                const float* __restrict__ w1,
                                const float* __restrict__ w2,
                                unsigned short* __restrict__ o) {
    int i = blockIdx.x * blockDim.x + threadIdx.x;
    if (i >= NB1 + NB2 + NB3) return;
    const float* src; int j = i;
    if (j < NB1) { src = g; }
    else if (j < NB1 + NB2) { src = w1; j -= NB1; }
    else { src = w2; j -= NB1 + NB2; }
    float4 v = reinterpret_cast<const float4*>(src)[j];
    ushort4 u;
    u.x = f2bf(v.x); u.y = f2bf(v.y); u.z = f2bf(v.z); u.w = f2bf(v.w);
    reinterpret_cast<ushort4*>(o)[i] = u;
}

#define GLDS16(gp, lp)                                                         \
    __builtin_amdgcn_global_load_lds(                                          \
        (__attribute__((address_space(1))) const void*)(gp),                   \
        (__attribute__((address_space(3))) void*)(lp), 16, 0, 0)

#define VMCNT(n) asm volatile("s_waitcnt vmcnt(" #n ")" ::: "memory")
#define SBAR()   __builtin_amdgcn_s_barrier()
#define SCHED0() __builtin_amdgcn_sched_barrier(0)

// ---------------- GEMM1: h = silu(gen @ w1^T), bf16 out (unchanged) ----------
__global__ __launch_bounds__(256) void gemm1_silu_kernel(
    const unsigned short* __restrict__ A,
    const unsigned short* __restrict__ Bm,
    unsigned short* __restrict__ H)
{
    __shared__ short smA[128 * 32];
    __shared__ short smB[128 * 32];
    const int m0   = blockIdx.y * 128;
    const int n0   = blockIdx.x * 128;
    const int lane = threadIdx.x & 63;
    const int wave = threadIdx.x >> 6;
    const int wm   = wave >> 1, wn = wave & 1;

    const int c0 = wave * 64 + lane;
    const int c1 = c0 + 256;
    const int rA0 = m0 + (c0 >> 2), rA1 = m0 + (c1 >> 2);
    const int rB0 = n0 + (c0 >> 2), rB1 = n0 + (c1 >> 2);
    const int ko0 = (c0 & 3) * 8,  ko1 = (c1 & 3) * 8;

    f32x4 acc[4][4] = {};

    for (int k0 = 0; k0 < DMm; k0 += 32) {
        GLDS16(A  + (size_t)rA0 * DMm + k0 + ko0, smA + wave * 512);
        GLDS16(A  + (size_t)rA1 * DMm + k0 + ko1, smA + 2048 + wave * 512);
        GLDS16(Bm + (size_t)rB0 * DMm + k0 + ko0, smB + wave * 512);
        GLDS16(Bm + (size_t)rB1 * DMm + k0 + ko1, smB + 2048 + wave * 512);
        __syncthreads();

        const int la = lane & 15, ko = (lane >> 4) * 8;
        bf16x8 af[4], bfr[4];
#pragma unroll
        for (int mm = 0; mm < 4; ++mm)
            af[mm] = *reinterpret_cast<const bf16x8*>(&smA[(wm * 64 + mm * 16 + la) * 32 + ko]);
#pragma unroll
        for (int nn = 0; nn < 4; ++nn)
            bfr[nn] = *reinterpret_cast<const bf16x8*>(&smB[(wn * 64 + nn * 16 + la) * 32 + ko]);
#pragma unroll
        for (int mm = 0; mm < 4; ++mm)
#pragma unroll
            for (int nn = 0; nn < 4; ++nn)
                acc[mm][nn] = __builtin_amdgcn_mfma_f32_16x16x32_bf16(
                    af[mm], bfr[nn], acc[mm][nn], 0, 0, 0);
        __syncthreads();
    }

#pragma unroll
    for (int mm = 0; mm < 4; ++mm) {
        int rowB = m0 + wm * 64 + mm * 16 + (lane >> 4) * 4;
#pragma unroll
        for (int nn = 0; nn < 4; ++nn) {
            int colG = n0 + wn * 64 + nn * 16 + (lane & 15);
#pragma unroll
            for (int j = 0; j < 4; ++j) {
                float v = acc[mm][nn][j];
                float s = v / (1.0f + __expf(-v));
                H[(size_t)(rowB + j) * DGg + colG] = f2bf(s);
            }
        }
    }
}

// ===== GEMM2 fused: 256n x 512t (two 256t tiles share A), ring-3, BK=32 =====
// D[n][t] = sum_k W2b[n][k] * Hb[t][k]   (n = 4d+w; conv taps w = acc reg idx j)
// 8 waves (wm 0..1 x wn 0..3); wave: aF[8] x (bF0[4], bF1[4]) -> 64 MFMA,
// 16 ds_read_b128 per region (0.25 b128/MFMA vs 0.375 in round 6).
// Rings: A[3 par][256 rows][64B] @0 (48K); B[3 par][2 tile][256 rows][64B]
// @49152 (96K). Stage-2-ahead both; region r reads parity r%3, stages tiles
// r+2 into parity (r+2)%3 (last read region r-1, certified by its barrier).
// Ledger (per-thread VMEM: B=4, A=2 per region, order B then A):
//   prologue [B0,A0,B1,A1] -> VMCNT(6) certifies tile 0, keeps tile 1 flying.
//   region r=0..13: stage B(r+2),A(r+2); VMCNT(6) keeps exactly those 6,
//   certifies tile r+1 for ALL waves before SBAR.  r=14: VMCNT(0). r=15 bare.
// x handled entirely post-loop (two reg-staged tiles, hidden under epi0).
// Epilogue overlay: smX f32[259][68] @0, smY f32[256][68] @70448.
#define LDS_Bb 49152

__global__ __launch_bounds__(512, 2) void gemm2_conv_silu_kernel(
    const unsigned short* __restrict__ Hb,
    const unsigned short* __restrict__ W2b,
    const float* __restrict__ b2,
    const float* __restrict__ x,
    float* __restrict__ out)
{
    __shared__ __attribute__((aligned(16))) char lds[147456];
    const int tid  = threadIdx.x;
    const int lane = tid & 63, wave = tid >> 6;
    const int wm   = wave >> 2, wn = wave & 3;
    const int la   = lane & 15, hi = lane >> 4;

    // XCD-aware swizzle (1024 blocks, %8==0 -> bijective); t fast within XCD
    int bid = blockIdx.x;
    int swz = (bid & 7) * 128 + (bid >> 3);
    const int n0 = (swz >> 4) * 256;   // 64 n-tiles
    const int t0 = (swz & 15) * 512;   // 16 t-pairs (512 tokens, same batch)
    const int d0 = n0 >> 2;

    const int srow = lane >> 2;
    const int scol = ((lane & 3) ^ ((srow >> 1) & 3)) * 8;   // pre-swizzled src col

    auto stageA = [&](int tk, int p) {   // 2 loads/thread
#pragma unroll
        for (int q = 0; q < 2; ++q) {
            int chunk = wave * 2 + q, row = chunk * 16 + srow;
            GLDS16(W2b + (size_t)(n0 + row) * DGg + tk * 32 + scol,
                   lds + p * 16384 + chunk * 1024);
        }
    };
    auto stageB = [&](int tk, int p) {   // 4 loads/thread (2 t-tiles)
#pragma unroll
        for (int tt = 0; tt < 2; ++tt)
#pragma unroll
            for (int q = 0; q < 2; ++q) {
                int chunk = wave * 2 + q, row = chunk * 16 + srow;
                GLDS16(Hb + (size_t)(t0 + tt * 256 + row) * DGg + tk * 32 + scol,
                       lds + LDS_Bb + p * 32768 + tt * 16384 + chunk * 1024);
            }
    };

    f32x4 accA[8][4] = {}, accB[8][4] = {};
    const int slotb = (hi ^ ((la >> 1) & 3)) * 16;   // swizzled 16B slot

    auto region = [&](int r, bool doStage) {
        const int p = r % 3;
        const char* aB = lds + p * 16384 + (wm * 128 + la) * 64 + slotb;
        const char* b0 = lds + LDS_Bb + p * 32768 + (wn * 64 + la) * 64 + slotb;
        const char* b1 = b0 + 16384;
        bf16x8 bF0[4], aF[8], bF1[4];
#pragma unroll
        for (int nr = 0; nr < 4; ++nr)   // bF0 first: accA MFMAs start early
            bF0[nr] = *reinterpret_cast<const bf16x8*>(b0 + nr * 1024);
#pragma unroll
        for (int m = 0; m < 8; ++m)
            aF[m] = *reinterpret_cast<const bf16x8*>(aB + m * 1024);
#pragma unroll
        for (int nr = 0; nr < 4; ++nr)
            bF1[nr] = *reinterpret_cast<const bf16x8*>(b1 + nr * 1024);
        if (doStage) { stageB(r + 2, (r + 2) % 3); stageA(r + 2, (r + 2) % 3); }
        SCHED0();
        __builtin_amdgcn_s_setprio(1);
#pragma unroll
        for (int m = 0; m < 8; ++m)
#pragma unroll
            for (int nr = 0; nr < 4; ++nr)
                accA[m][nr] = __builtin_amdgcn_mfma_f32_16x16x32_bf16(
                    aF[m], bF0[nr], accA[m][nr], 0, 0, 0);
#pragma unroll
        for (int m = 0; m < 8; ++m)
#pragma unroll
            for (int nr = 0; nr < 4; ++nr)
                accB[m][nr] = __builtin_amdgcn_mfma_f32_16x16x32_bf16(
                    aF[m], bF1[nr], accB[m][nr], 0, 0, 0);
        __builtin_amdgcn_s_setprio(0);
        SCHED0();
    };

    // ---- prologue: tiles 0,1 staged; counted drain certifies tile 0 ----
    stageB(0, 0); stageA(0, 0); stageB(1, 1); stageA(1, 1);
    VMCNT(6);
    SBAR();

    // ---- main loop ----
    for (int r = 0; r < 14; ++r) {
        region(r, true);
        VMCNT(6);          // tile r+1 landed for all waves; tile r+2 in flight
        SBAR();
    }
    region(14, false); VMCNT(0); SBAR();   // tile 15 landed
    region(15, false);

    // ---- x loads for both tiles (issued before LDS overlay barrier) ----
    float4 xa[9], xb[9];
#pragma unroll
    for (int k = 0; k < 9; ++k) {
        int c = tid + k * 512;             // < 4144 = 259 rows * 16 chunks
        float4 v0 = make_float4(0.f, 0.f, 0.f, 0.f);
        float4 v1 = make_float4(0.f, 0.f, 0.f, 0.f);
        if (c < 4144) {
            int row = c >> 4, q = c & 15;
            int rg0 = t0 - 3 + row;
            if (rg0 >= 0 && (rg0 >> 12) == (t0 >> 12))
                v0 = *reinterpret_cast<const float4*>(&x[(size_t)rg0 * DD + d0 + q * 4]);
            int rg1 = t0 + 253 + row;      // (t0+256)-3+row, always in-batch
            v1 = *reinterpret_cast<const float4*>(&x[(size_t)rg1 * DD + d0 + q * 4]);
        }
        xa[k] = v0; xb[k] = v1;
    }
    __syncthreads();   // all K-loop LDS reads done; overlay smX/smY

    float* smX = reinterpret_cast<float*>(lds);
    float* smY = reinterpret_cast<float*>(lds + 70448);

    float4 bb[8];
#pragma unroll
    for (int m = 0; m < 8; ++m)
        bb[m] = *reinterpret_cast<const float4*>(&b2[n0 + wm * 128 + m * 16 + hi * 4]);

    // tile 0: X write, epi, store
#pragma unroll
    for (int k = 0; k < 9; ++k) {
        int c = tid + k * 512;
        if (c < 4144) {
            int row = c >> 4, q = c & 15;
            *reinterpret_cast<float4*>(&smX[row * 68 + q * 4]) = xa[k];
        }
    }
    __syncthreads();
#pragma unroll
    for (int nr = 0; nr < 4; ++nr) {
        int tl = wn * 64 + nr * 16 + la;
#pragma unroll
        for (int m = 0; m < 8; ++m) {
            int dl = wm * 32 + m * 4 + hi;
            float pv =
                  (accA[m][nr][0] + bb[m].x) * smX[(tl + 0) * 68 + dl]
                + (accA[m][nr][1] + bb[m].y) * smX[(tl + 1) * 68 + dl]
                + (accA[m][nr][2] + bb[m].z) * smX[(tl + 2) * 68 + dl]
                + (accA[m][nr][3] + bb[m].w) * smX[(tl + 3) * 68 + dl];
            smY[tl * 68 + dl] = pv / (1.0f + __expf(-pv));
        }
    }
    __syncthreads();
    for (int c = tid; c < 256 * 16; c += 512) {
        int row = c >> 4, q = c & 15;
        float4 v = *reinterpret_cast<const float4*>(&smY[row * 68 + q * 4]);
        *reinterpret_cast<float4*>(&out[(size_t)(t0 + row) * DD + d0 + q * 4]) = v;
    }
    // tile 1 X write may start once epi0's smX reads are done; stores of tile 0
    // read smY only, so they proceed concurrently after this barrier.
    __syncthreads();
#pragma unroll
    for (int k = 0; k < 9; ++k) {
        int c = tid + k * 512;
        if (c < 4144) {
            int row = c >> 4, q = c & 15;
            *reinterpret_cast<float4*>(&smX[row * 68 + q * 4]) = xb[k];
        }
    }
    __syncthreads();   // smX ready AND tile-0 stores (smY reads) done
#pragma unroll
    for (int nr = 0; nr < 4; ++nr) {
        int tl = wn * 64 + nr * 16 + la;
#pragma unroll
        for (int m = 0; m < 8; ++m) {
            int dl = wm * 32 + m * 4 + hi;
            float pv =
                  (accB[m][nr][0] + bb[m].x) * smX[(tl + 0) * 68 + dl]
                + (accB[m][nr][1] + bb[m].y) * smX[(tl + 1) * 68 + dl]
                + (accB[m][nr][2] + bb[m].z) * smX[(tl + 2) * 68 + dl]
                + (accB[m][nr][3] + bb[m].w) * smX[(tl + 3) * 68 + dl];
            smY[tl * 68 + dl] = pv / (1.0f + __expf(-pv));
        }
    }
    __syncthreads();
    for (int c = tid; c < 256 * 16; c += 512) {
        int row = c >> 4, q = c & 15;
        float4 v = *reinterpret_cast<const float4*>(&smY[row * 68 + q * 4]);
        *reinterpret_cast<float4*>(&out[(size_t)(t0 + 256 + row) * DD + d0 + q * 4]) = v;
    }
}

extern "C" void kernel_launch(void* const* d_in, const int* in_sizes, int n_in,
                              void* d_out, int out_size, void* d_ws, size_t ws_size,
                              hipStream_t stream) {
    const float* x   = (const float*)d_in[0];
    const float* gen = (const float*)d_in[1];
    const float* w1  = (const float*)d_in[2];
    const float* w2  = (const float*)d_in[3];
    const float* b2  = (const float*)d_in[4];
    float* out = (float*)d_out;

    char* ws = (char*)d_ws;
    size_t off = 0;
    unsigned short* gen_b = (unsigned short*)(ws + off); off += (size_t)BT * DMm * 2;
    unsigned short* w1_b  = (unsigned short*)(ws + off); off += (size_t)DGg * DMm * 2;
    unsigned short* w2_b  = (unsigned short*)(ws + off); off += (size_t)DW * DGg * 2;
    unsigned short* h_b   = (unsigned short*)(ws + off); off += (size_t)BT * DGg * 2;

    int total4 = NB1 + NB2 + NB3;
    cast_all_kernel<<<(total4 + 255) / 256, 256, 0, stream>>>(gen, w1, w2, gen_b);

    gemm1_silu_kernel<<<dim3(DGg / 128, BT / 128), 256, 0, stream>>>(gen_b, w1_b, h_b);
    gemm2_conv_silu_kernel<<<1024, 512, 0, stream>>>(h_b, w2_b, b2, x, out);
}

// Round 8
// 261.058 us; speedup vs baseline: 4.6354x; 4.6354x over previous
//
#include <hip/hip_runtime.h>
#include <hip/hip_bf16.h>
#include <stdint.h>

// Problem constants
#define TLEN 4096
#define DMm  2048
#define DD   4096
#define DGg  512
#define BT   8192          // B*T
#define DW   16384         // D*W

typedef __attribute__((ext_vector_type(8))) short bf16x8;
typedef __attribute__((ext_vector_type(4))) float f32x4;

__device__ __forceinline__ unsigned short f2bf(float f) {
    union { float f; unsigned u; } c; c.f = f;
    unsigned u = c.u;
    unsigned r = (u + 0x7FFFu + ((u >> 16) & 1u)) >> 16;   // RNE
    return (unsigned short)r;
}

// ---------------- fused cast f32 -> bf16 for gen|w1|w2 (contiguous in ws) ----
#define NB1 (BT * DMm / 4)
#define NB2 (DGg * DMm / 4)
#define NB3 (DW * DGg / 4)
__global__ void cast_all_kernel(const float* __restrict__ g,
                                const float* __restrict__ w1,
                                const float* __restrict__ w2,
                                unsigned short* __restrict__ o) {
    int i = blockIdx.x * blockDim.x + threadIdx.x;
    if (i >= NB1 + NB2 + NB3) return;
    const float* src; int j = i;
    if (j < NB1) { src = g; }
    else if (j < NB1 + NB2) { src = w1; j -= NB1; }
    else { src = w2; j -= NB1 + NB2; }
    float4 v = reinterpret_cast<const float4*>(src)[j];
    ushort4 u;
    u.x = f2bf(v.x); u.y = f2bf(v.y); u.z = f2bf(v.z); u.w = f2bf(v.w);
    reinterpret_cast<ushort4*>(o)[i] = u;
}

#define GLDS16(gp, lp)                                                         \
    __builtin_amdgcn_global_load_lds(                                          \
        (__attribute__((address_space(1))) const void*)(gp),                   \
        (__attribute__((address_space(3))) void*)(lp), 16, 0, 0)

#define VMCNT(n) asm volatile("s_waitcnt vmcnt(" #n ")" ::: "memory")
#define SBAR()   __builtin_amdgcn_s_barrier()
#define SCHED0() __builtin_amdgcn_sched_barrier(0)

// ---------------- GEMM1: h = silu(gen @ w1^T), bf16 out (unchanged) ----------
__global__ __launch_bounds__(256) void gemm1_silu_kernel(
    const unsigned short* __restrict__ A,
    const unsigned short* __restrict__ Bm,
    unsigned short* __restrict__ H)
{
    __shared__ short smA[128 * 32];
    __shared__ short smB[128 * 32];
    const int m0   = blockIdx.y * 128;
    const int n0   = blockIdx.x * 128;
    const int lane = threadIdx.x & 63;
    const int wave = threadIdx.x >> 6;
    const int wm   = wave >> 1, wn = wave & 1;

    const int c0 = wave * 64 + lane;
    const int c1 = c0 + 256;
    const int rA0 = m0 + (c0 >> 2), rA1 = m0 + (c1 >> 2);
    const int rB0 = n0 + (c0 >> 2), rB1 = n0 + (c1 >> 2);
    const int ko0 = (c0 & 3) * 8,  ko1 = (c1 & 3) * 8;

    f32x4 acc[4][4] = {};

    for (int k0 = 0; k0 < DMm; k0 += 32) {
        GLDS16(A  + (size_t)rA0 * DMm + k0 + ko0, smA + wave * 512);
        GLDS16(A  + (size_t)rA1 * DMm + k0 + ko1, smA + 2048 + wave * 512);
        GLDS16(Bm + (size_t)rB0 * DMm + k0 + ko0, smB + wave * 512);
        GLDS16(Bm + (size_t)rB1 * DMm + k0 + ko1, smB + 2048 + wave * 512);
        __syncthreads();

        const int la = lane & 15, ko = (lane >> 4) * 8;
        bf16x8 af[4], bfr[4];
#pragma unroll
        for (int mm = 0; mm < 4; ++mm)
            af[mm] = *reinterpret_cast<const bf16x8*>(&smA[(wm * 64 + mm * 16 + la) * 32 + ko]);
#pragma unroll
        for (int nn = 0; nn < 4; ++nn)
            bfr[nn] = *reinterpret_cast<const bf16x8*>(&smB[(wn * 64 + nn * 16 + la) * 32 + ko]);
#pragma unroll
        for (int mm = 0; mm < 4; ++mm)
#pragma unroll
            for (int nn = 0; nn < 4; ++nn)
                acc[mm][nn] = __builtin_amdgcn_mfma_f32_16x16x32_bf16(
                    af[mm], bfr[nn], acc[mm][nn], 0, 0, 0);
        __syncthreads();
    }

#pragma unroll
    for (int mm = 0; mm < 4; ++mm) {
        int rowB = m0 + wm * 64 + mm * 16 + (lane >> 4) * 4;
#pragma unroll
        for (int nn = 0; nn < 4; ++nn) {
            int colG = n0 + wn * 64 + nn * 16 + (lane & 15);
#pragma unroll
            for (int j = 0; j < 4; ++j) {
                float v = acc[mm][nn][j];
                float s = v / (1.0f + __expf(-v));
                H[(size_t)(rowB + j) * DGg + colG] = f2bf(s);
            }
        }
    }
}

// ===== GEMM2 fused: 256n x 256t, quad-ring BK=32, A-fragment prefetch =====
// D[n][t] = sum_k W2b[n][k] * Hb[t][k]   (n = 4d+w; conv taps w = acc reg idx j)
// 8 waves (wm 0..1 x wn 0..3); wave 128n x 64t: aF[8] x bF[4] -> 32 MFMA,
// 12 ds_read_b128 per region.  NEW vs round 6: A-frags for region r+1 are
// read BEFORE region r's MFMA cluster (double-buffered aFa/aFb), so 8 of 12
// reads drain under the MFMA.  Enabled by deepening certification: VMCNT(4)
// at region r certifies tile r+2 (round 6's VMCNT(8) only certified r+1),
// so at region r's start tile r+1 is readable.  Ledger (4 loads/thread/tile):
//   prologue stages 0,1,2 (12); VMCNT(4) certifies {0,1}, tile 2 in flight.
//   region r (0..12): stage r+3; VMCNT(4) certifies r+2, r+3 in flight.
//   r=13: VMCNT(0) certifies 15.  r=14, 15: bare.
// LDS: A[4 par][256][64B] @0 (64K), B same @65536 (64K);
//      post-loop overlay X f32[259][68] @0, Y f32[256][68] @70448.
#define LDS_B2 65536

__global__ __launch_bounds__(512, 2) void gemm2_conv_silu_kernel(
    const unsigned short* __restrict__ Hb,
    const unsigned short* __restrict__ W2b,
    const float* __restrict__ b2,
    const float* __restrict__ x,
    float* __restrict__ out)
{
    __shared__ __attribute__((aligned(16))) char lds[140080];
    const int tid  = threadIdx.x;
    const int lane = tid & 63, wave = tid >> 6;
    const int wm   = wave >> 2, wn = wave & 3;
    const int la   = lane & 15, hi = lane >> 4;

    // XCD-aware swizzle (2048 blocks, %8==0 -> bijective)
    int bid = blockIdx.x;
    int swz = (bid & 7) * 256 + (bid >> 3);
    const int n0 = (swz >> 5) * 256;   // 64 n-tiles
    const int t0 = (swz & 31) * 256;   // 32 t-tiles
    const int d0 = n0 >> 2;

    const int srow = lane >> 2;
    const int scol = ((lane & 3) ^ ((srow >> 1) & 3)) * 8;   // pre-swizzled src col

    auto stageA = [&](int tk, int p) {   // 2 loads/thread: 16KB tile
#pragma unroll
        for (int q = 0; q < 2; ++q) {
            int chunk = wave * 2 + q, row = chunk * 16 + srow;
            GLDS16(W2b + (size_t)(n0 + row) * DGg + tk * 32 + scol,
                   lds + p * 16384 + chunk * 1024);
        }
    };
    auto stageB = [&](int tk, int p) {   // 2 loads/thread: 16KB tile
#pragma unroll
        for (int q = 0; q < 2; ++q) {
            int chunk = wave * 2 + q, row = chunk * 16 + srow;
            GLDS16(Hb + (size_t)(t0 + row) * DGg + tk * 32 + scol,
                   lds + LDS_B2 + p * 16384 + chunk * 1024);
        }
    };

    f32x4 acc[8][4] = {};
    const int slotb = (hi ^ ((la >> 1) & 3)) * 16;   // swizzled 16B slot
    const int aOff  = (wm * 128 + la) * 64 + slotb;
    const int bOff  = (wn * 64 + la) * 64 + slotb;

    bf16x8 aFa[8], aFb[8];

    auto rdA = [&](bf16x8 (&dst)[8], int p) {
        const char* aB = lds + p * 16384 + aOff;
#pragma unroll
        for (int m = 0; m < 8; ++m)
            dst[m] = *reinterpret_cast<const bf16x8*>(aB + m * 1024);
    };

    // Region body: bF reads (cur) + A-prefetch (next) + stage, then MFMA(AC).
    // Compiler's automatic lgkm tracking waits only on consumed frags; AN has
    // no use here, so its 8 reads stay outstanding under the MFMA cluster.
    auto body = [&](bf16x8 (&AC)[8], bf16x8 (&AN)[8], int pcur, int pnext,
                    int tkS, bool doStage, bool doPre) {
        bf16x8 bF[4];
        const char* bB = lds + LDS_B2 + pcur * 16384 + bOff;
#pragma unroll
        for (int nr = 0; nr < 4; ++nr)
            bF[nr] = *reinterpret_cast<const bf16x8*>(bB + nr * 1024);
        if (doPre) rdA(AN, pnext);
        if (doStage) { stageA(tkS, tkS & 3); stageB(tkS, tkS & 3); }
        SCHED0();   // pin reads+stage above the MFMA cluster
        __builtin_amdgcn_s_setprio(1);
#pragma unroll
        for (int m = 0; m < 8; ++m)
#pragma unroll
            for (int nr = 0; nr < 4; ++nr)
                acc[m][nr] = __builtin_amdgcn_mfma_f32_16x16x32_bf16(
                    AC[m], bF[nr], acc[m][nr], 0, 0, 0);
        __builtin_amdgcn_s_setprio(0);
        SCHED0();
    };

    // ---- prologue ----
    stageA(0, 0); stageB(0, 0);
    stageA(1, 1); stageB(1, 1);
    stageA(2, 2); stageB(2, 2);
    VMCNT(4);     // tiles 0,1 certified for all waves after the barrier
    SBAR();
    rdA(aFa, 0);  // region-0 A frags; drain under region-0's bF wait

    // ---- main loop: regions 0..12 stage tile r+3 ----
#pragma unroll
    for (int r = 0; r < 13; ++r) {
        if (r & 1) body(aFb, aFa, r & 3, (r + 1) & 3, r + 3, true, true);
        else       body(aFa, aFb, r & 3, (r + 1) & 3, r + 3, true, true);
        VMCNT(4);   // certify tile r+2; tile r+3 (4 loads) in flight
        SBAR();
    }
    body(aFb, aFa, 1, 2, 0, false, true);  VMCNT(0); SBAR();  // r=13, certify 15
    body(aFa, aFb, 2, 3, 0, false, true);  SBAR();            // r=14
    body(aFb, aFa, 3, 0, 0, false, false);                    // r=15

    // ---- x loads (after loop; ride in regs until overlay is safe) ----
    float4 xv[9];
#pragma unroll
    for (int k = 0; k < 9; ++k) {
        int c = tid + k * 512;                   // < 4144 = 259 rows * 16 chunks
        float4 v = make_float4(0.f, 0.f, 0.f, 0.f);
        if (c < 4144) {
            int row = c >> 4, q = c & 15;
            int rg = t0 - 3 + row;
            if (rg >= 0 && (rg >> 12) == (t0 >> 12))   // zero across batch boundary
                v = *reinterpret_cast<const float4*>(&x[(size_t)rg * DD + d0 + q * 4]);
        }
        xv[k] = v;
    }
    __syncthreads();   // all K-loop LDS reads done; overlay X/Y

    float* smX = reinterpret_cast<float*>(lds);
#pragma unroll
    for (int k = 0; k < 9; ++k) {
        int c = tid + k * 512;
        if (c < 4144) {
            int row = c >> 4, q = c & 15;
            *reinterpret_cast<float4*>(&smX[row * 68 + q * 4]) = xv[k];
        }
    }
    __syncthreads();

    // ---- epilogue: bias + conv taps (reg idx j) + silu -> smY ----
    float4 bb[8];
#pragma unroll
    for (int m = 0; m < 8; ++m)
        bb[m] = *reinterpret_cast<const float4*>(&b2[n0 + wm * 128 + m * 16 + hi * 4]);

    float* smY = reinterpret_cast<float*>(lds + 70448);
#pragma unroll
    for (int nr = 0; nr < 4; ++nr) {
        int tl = wn * 64 + nr * 16 + la;
#pragma unroll
        for (int m = 0; m < 8; ++m) {
            int dl = wm * 32 + m * 4 + hi;
            float pv =
                  (acc[m][nr][0] + bb[m].x) * smX[(tl + 0) * 68 + dl]
                + (acc[m][nr][1] + bb[m].y) * smX[(tl + 1) * 68 + dl]
                + (acc[m][nr][2] + bb[m].z) * smX[(tl + 2) * 68 + dl]
                + (acc[m][nr][3] + bb[m].w) * smX[(tl + 3) * 68 + dl];
            smY[tl * 68 + dl] = pv / (1.0f + __expf(-pv));
        }
    }
    __syncthreads();

    // ---- coalesced store: 256 rows x 64 f32 (256 B per row) ----
    for (int c = tid; c < 256 * 16; c += 512) {
        int row = c >> 4, q = c & 15;
        float4 v = *reinterpret_cast<const float4*>(&smY[row * 68 + q * 4]);
        *reinterpret_cast<float4*>(&out[(size_t)(t0 + row) * DD + d0 + q * 4]) = v;
    }
}

extern "C" void kernel_launch(void* const* d_in, const int* in_sizes, int n_in,
                              void* d_out, int out_size, void* d_ws, size_t ws_size,
                              hipStream_t stream) {
    const float* x   = (const float*)d_in[0];
    const float* gen = (const float*)d_in[1];
    const float* w1  = (const float*)d_in[2];
    const float* w2  = (const float*)d_in[3];
    const float* b2  = (const float*)d_in[4];
    float* out = (float*)d_out;

    char* ws = (char*)d_ws;
    size_t off = 0;
    unsigned short* gen_b = (unsigned short*)(ws + off); off += (size_t)BT * DMm * 2;
    unsigned short* w1_b  = (unsigned short*)(ws + off); off += (size_t)DGg * DMm * 2;
    unsigned short* w2_b  = (unsigned short*)(ws + off); off += (size_t)DW * DGg * 2;
    unsigned short* h_b   = (unsigned short*)(ws + off); off += (size_t)BT * DGg * 2;

    int total4 = NB1 + NB2 + NB3;
    cast_all_kernel<<<(total4 + 255) / 256, 256, 0, stream>>>(gen, w1, w2, gen_b);

    gemm1_silu_kernel<<<dim3(DGg / 128, BT / 128), 256, 0, stream>>>(gen_b, w1_b, h_b);
    gemm2_conv_silu_kernel<<<2048, 512, 0, stream>>>(h_b, w2_b, b2, x, out);
}